// Round 9
// baseline (21.013 us; speedup 1.0000x reference)
//
#include <hip/hip_runtime.h>
#include <math.h>

// Gaussian splat forward: N gaussians -> res x res image (res=256, N=1024).
// ONE kernel, ZERO atomics, ZERO memsets, and ZERO LDS in the main loop:
//   grid = nt*nt = 256 blocks (one per 16x16 tile) x 1024 threads (16 waves).
//   Phase 1: thread t preps gaussian t's expanded quadratic
//     q = A X^2 + B Y^2 + C XY + c3 X + c4 Y + c5   (log2 domain, opacity
//     folded in; this tile's mask folds c5 -> -inf; pad lanes too)
//     into SIX REGISTERS. Wave w's lanes hold gaussians [w*64, w*64+63].
//   Phase 2: wave w loops i=0..63 (fully unrolled) broadcasting lane i's
//     coefficients via v_readlane (VALU pipe, no LDS traffic). Each FMA is
//     arranged to use exactly ONE scalar operand (VOP3 limit). Delta-form
//     2x2 quad eval: qaa direct, qba=qaa+dX, qab=qaa+dY, qbb=qab+dX+C.
//     c5=-inf propagates additively to all 4 pixels (exp2->0, no inf*0).
//     No barrier between prep and main loop (registers are wave-private).
//   Phase 3: 16-wave LDS reduce (only LDS use, 16KB); wave 0 writes each
//     pixel exactly once with coalesced float2 stores (full overwrite).

#define TILE 16
#define NW    16           // waves per block (1024 threads)
#define CHUNK 1024         // gaussians per outer chunk (== block threads)

__device__ __forceinline__ float rlane(float v, int lane) {
    return __uint_as_float(
        (unsigned)__builtin_amdgcn_readlane((int)__float_as_uint(v), lane));
}

__global__ __launch_bounds__(1024, 1) void gs_fused(
    const float* __restrict__ xyz, const float* __restrict__ scaling,
    const float* __restrict__ rotation, const float* __restrict__ opacity,
    const float* __restrict__ rot, float* __restrict__ out,
    int N, int res, int nt)
{
    __shared__ float4 sR[NW][64];    // per-wave partial 2x2 quads

    const int tid = threadIdx.x;
    const int w = tid >> 6, l = tid & 63;
    const int tX = blockIdx.x % nt, tY = blockIdx.x / nt;
    const float resf = (float)res;

    // this lane's 2x2 pixel quad (each wave covers the whole 16x16 tile)
    const int px0 = tX * TILE + (l & 7) * 2;
    const int py0 = tY * TILE + (l >> 3) * 2;
    const float ctr = resf * 0.5f - 0.5f;
    const float Xa = (float)px0 - ctr;
    const float Ya = (float)py0 - ctr;
    const float Xa2 = Xa * Xa, Ya2 = Ya * Ya, XaYa = Xa * Ya;
    const float sXab = 2.f * Xa + 1.f;
    const float sYab = 2.f * Ya + 1.f;

    const float tx0 = (float)(tX * TILE), tx1 = tx0 + (float)(TILE - 1);
    const float ty0 = (float)(tY * TILE), ty1 = ty0 + (float)(TILE - 1);

    float acc00 = 0.f, acc10 = 0.f, acc01 = 0.f, acc11 = 0.f;

    for (int base = 0; base < N; base += CHUNK) {
        // ---------- per-thread prep of gaussian (base+tid) into registers ----------
        float cA = 0.f, cB = 0.f, cC = 0.f, cc3 = 0.f, cc4 = 0.f, cc5 = -INFINITY;
        int n = base + tid;
        if (n < N) {
            float qr = rotation[4*n+0], qx = rotation[4*n+1];
            float qy = rotation[4*n+2], qz = rotation[4*n+3];
            float inv = 1.0f / sqrtf(qr*qr + qx*qx + qy*qy + qz*qz);
            float r = qr*inv, x = qx*inv, y = qy*inv, z = qz*inv;

            float R00 = 1.f - 2.f*(y*y + z*z), R01 = 2.f*(x*y - r*z), R02 = 2.f*(x*z + r*y);
            float R10 = 2.f*(x*y + r*z), R11 = 1.f - 2.f*(x*x + z*z), R12 = 2.f*(y*z - r*x);
            float R20 = 2.f*(x*z - r*y), R21 = 2.f*(y*z + r*x), R22 = 1.f - 2.f*(x*x + y*y);

            float s0 = scaling[3*n+0], s1 = scaling[3*n+1], s2 = scaling[3*n+2];
            float L00 = R00*s0, L01 = R01*s1, L02 = R02*s2;
            float L10 = R10*s0, L11 = R11*s1, L12 = R12*s2;
            float L20 = R20*s0, L21 = R21*s1, L22 = R22*s2;

            float a00 = resf*rot[0], a01 = resf*rot[1], a02 = resf*rot[2];
            float a10 = resf*rot[3], a11 = resf*rot[4], a12 = resf*rot[5];
            float b00 = a00*L00 + a01*L10 + a02*L20;
            float b01 = a00*L01 + a01*L11 + a02*L21;
            float b02 = a00*L02 + a01*L12 + a02*L22;
            float b10 = a10*L00 + a11*L10 + a12*L20;
            float b11 = a10*L01 + a11*L11 + a12*L21;
            float b12 = a10*L02 + a11*L12 + a12*L22;
            float c00 = b00*b00 + b01*b01 + b02*b02;
            float c01 = b00*b10 + b01*b11 + b02*b12;   // == c10
            float c11 = b10*b10 + b11*b11 + b12*b12;

            float det = c00*c11 - c01*c01;
            float mid = 0.5f*(c00 + c11);
            float sq  = sqrtf(fmaxf(mid*mid - det, 0.1f));
            float lam = fmaxf(mid + sq, mid - sq);
            float radii = ceilf(3.0f * sqrtf(lam));

            float mx = xyz[3*n+0] * (resf*0.5f);
            float my = xyz[3*n+1] * (resf*0.5f);
            float rminx = fminf(fmaxf(mx - radii, 0.f), resf - 1.f);
            float rmaxx = fminf(fmaxf(mx + radii, 0.f), resf - 1.f);
            float rminy = fminf(fmaxf(my - radii, 0.f), resf - 1.f);
            float rmaxy = fminf(fmaxf(my + radii, 0.f), resf - 1.f);

            bool pass = (fminf(rmaxx, tx1) > fmaxf(rminx, tx0)) &&
                        (fminf(rmaxy, ty1) > fmaxf(rminy, ty0));

            float idet = 1.0f / det;
            const float L2E = 1.44269504088896340736f;
            cA = -0.5f * L2E * c11 * idet;
            cB = -0.5f * L2E * c00 * idet;
            cC =         L2E * c01 * idet;

            cc3 = -2.f*cA*mx - cC*my;
            cc4 = -2.f*cB*my - cC*mx;
            float c5 = cA*mx*mx + cB*my*my + cC*mx*my + log2f(opacity[n]);
            cc5 = pass ? c5 : -INFINITY;
        }

        // ---------- main loop: broadcast lane i's coeffs via readlane ----------
        // (no barrier needed: each wave consumes only its own lanes' registers)
        #pragma unroll
        for (int i = 0; i < 64; ++i) {
            float A  = rlane(cA,  i);
            float B  = rlane(cB,  i);
            float C  = rlane(cC,  i);
            float s3 = rlane(cc3, i);
            float s4 = rlane(cc4, i);
            float s5 = rlane(cc5, i);
            // every op below has at most ONE scalar (SGPR) operand
            float t0  = A * Xa2;
            float t1  = fmaf(B, Ya2, t0);
            float t2  = fmaf(C, XaYa, t1);
            float t3  = fmaf(s3, Xa, t2);
            float t4  = fmaf(s4, Ya, t3);
            float qaa = t4 + s5;               // -inf if masked
            float d0  = A * sXab;
            float d1  = fmaf(C, Ya, d0);
            float dX  = d1 + s3;
            float e0  = B * sYab;
            float e1  = fmaf(C, Xa, e0);
            float dY  = e1 + s4;
            float qba = qaa + dX;
            float qab = qaa + dY;
            float dX2 = dX + C;
            float qbb = qab + dX2;
            acc00 += __builtin_amdgcn_exp2f(qaa);
            acc10 += __builtin_amdgcn_exp2f(qba);
            acc01 += __builtin_amdgcn_exp2f(qab);
            acc11 += __builtin_amdgcn_exp2f(qbb);
        }
    }

    // ---------- 16-wave reduce in LDS, plain stores (each pixel written once) ----------
    sR[w][l] = make_float4(acc00, acc10, acc01, acc11);
    __syncthreads();
    if (w == 0) {
        float4 s = sR[0][l];
        #pragma unroll
        for (int k = 1; k < NW; ++k) {
            float4 t = sR[k][l];
            s.x += t.x; s.y += t.y; s.z += t.z; s.w += t.w;
        }
        float* o = out + py0 * res + px0;
        *(float2*)(o)       = make_float2(s.x, s.y);
        *(float2*)(o + res) = make_float2(s.z, s.w);
    }
}

extern "C" void kernel_launch(void* const* d_in, const int* in_sizes, int n_in,
                              void* d_out, int out_size, void* d_ws, size_t ws_size,
                              hipStream_t stream) {
    const float* xyz      = (const float*)d_in[0];
    const float* scaling  = (const float*)d_in[1];
    const float* rotation = (const float*)d_in[2];
    const float* opacity  = (const float*)d_in[3];
    const float* rot      = (const float*)d_in[4];
    int N   = in_sizes[0] / 3;
    int res = (int)(sqrt((double)out_size) + 0.5);
    int nt  = res / TILE;

    float* out = (float*)d_out;

    gs_fused<<<dim3(nt * nt), 1024, 0, stream>>>(
        xyz, scaling, rotation, opacity, rot, out, N, res, nt);
}

// Round 10
// 18.315 us; speedup vs baseline: 1.1473x; 1.1473x over previous
//
#include <hip/hip_runtime.h>
#include <math.h>

// Gaussian splat forward: N gaussians -> res x res image (res=256, N=1024).
// ONE kernel, ZERO atomics, ZERO memsets (R8 structure + packed-FP32 inner loop):
//   grid = nt*nt = 256 blocks (one per 16x16 tile) x 1024 threads (16 waves).
//   Phase 1: block preps ALL gaussians (1/thread) into LDS: expanded
//     quadratic q = A X^2 + B Y^2 + C XY + c3 X + c4 Y + c5 (log2 domain,
//     opacity folded in; this tile's mask folds c5 -> -inf; pads too).
//   Phase 2: wave w accumulates gaussians [w*64, (w+1)*64) over the FULL
//     256-px tile (2x2 quad per lane). LDS reads are wave-uniform broadcasts.
//     PACKED eval: Q1=(q_aa,q_ab) via v_pk_fma chain; DX=(dX_a,dX_b);
//     Q2 = Q1 + DX. 7 scalar + 5 packed VALU + 4 exp2 per gaussian
//     (24 VALU-cyc vs 32 trans-cyc -> exp2-bound, the structural floor).
//     Masked c5=-inf enters additively -> all 4 exp2 -> 0, never inf*0.
//   Phase 3: 16-wave LDS reduce; wave 0 writes each pixel exactly once with
//     plain coalesced float2 stores. Full overwrite -> no init required.

#define TILE 16
#define MAXG 1024        // gaussians staged per chunk (N==1024 -> one chunk)
#define NW   16          // waves per block
#define GPW  (MAXG / NW) // gaussians per wave per chunk

typedef float v2f __attribute__((ext_vector_type(2)));

__global__ __launch_bounds__(1024, 1) void gs_fused(
    const float* __restrict__ xyz, const float* __restrict__ scaling,
    const float* __restrict__ rotation, const float* __restrict__ opacity,
    const float* __restrict__ rot, float* __restrict__ out,
    int N, int res, int nt)
{
    __shared__ float4 sP[MAXG];      // A, B, C, c3
    __shared__ float2 sQ[MAXG];      // c4, c5eff (-inf if masked/pad)
    __shared__ float4 sR[NW][64];    // per-wave partial 2x2 quads

    const int tid = threadIdx.x;
    const int w = tid >> 6, l = tid & 63;
    const int tX = blockIdx.x % nt, tY = blockIdx.x / nt;
    const float resf = (float)res;

    // this lane's 2x2 pixel quad (each wave covers the whole 16x16 tile)
    const int px0 = tX * TILE + (l & 7) * 2;
    const int py0 = tY * TILE + (l >> 3) * 2;
    const float ctr = resf * 0.5f - 0.5f;
    const float Xa = (float)px0 - ctr;
    const float Ya = (float)py0 - ctr, Yb = Ya + 1.f;
    const float Xa2 = Xa * Xa;
    const float sXab = 2.f * Xa + 1.f;       // (Xa+Xb)
    const v2f Yv  = {Ya, Yb};
    const v2f Y2v = {Ya * Ya, Yb * Yb};
    const v2f XYv = {Xa * Ya, Xa * Yb};

    const float tx0 = (float)(tX * TILE), tx1 = tx0 + (float)(TILE - 1);
    const float ty0 = (float)(tY * TILE), ty1 = ty0 + (float)(TILE - 1);

    float acc00 = 0.f, acc10 = 0.f, acc01 = 0.f, acc11 = 0.f;

    for (int base = 0; base < N; base += MAXG) {
        const int C = min(MAXG, N - base);

        // ---------- stage this chunk's coefficients into LDS ----------
        for (int slot = tid; slot < MAXG; slot += 1024) {
            float4 P = make_float4(0.f, 0.f, 0.f, 0.f);
            float2 Q = make_float2(0.f, -INFINITY);
            if (slot < C) {
                int n = base + slot;
                float qr = rotation[4*n+0], qx = rotation[4*n+1];
                float qy = rotation[4*n+2], qz = rotation[4*n+3];
                float inv = 1.0f / sqrtf(qr*qr + qx*qx + qy*qy + qz*qz);
                float r = qr*inv, x = qx*inv, y = qy*inv, z = qz*inv;

                float R00 = 1.f - 2.f*(y*y + z*z), R01 = 2.f*(x*y - r*z), R02 = 2.f*(x*z + r*y);
                float R10 = 2.f*(x*y + r*z), R11 = 1.f - 2.f*(x*x + z*z), R12 = 2.f*(y*z - r*x);
                float R20 = 2.f*(x*z - r*y), R21 = 2.f*(y*z + r*x), R22 = 1.f - 2.f*(x*x + y*y);

                float s0 = scaling[3*n+0], s1 = scaling[3*n+1], s2 = scaling[3*n+2];
                float L00 = R00*s0, L01 = R01*s1, L02 = R02*s2;
                float L10 = R10*s0, L11 = R11*s1, L12 = R12*s2;
                float L20 = R20*s0, L21 = R21*s1, L22 = R22*s2;

                float a00 = resf*rot[0], a01 = resf*rot[1], a02 = resf*rot[2];
                float a10 = resf*rot[3], a11 = resf*rot[4], a12 = resf*rot[5];
                float b00 = a00*L00 + a01*L10 + a02*L20;
                float b01 = a00*L01 + a01*L11 + a02*L21;
                float b02 = a00*L02 + a01*L12 + a02*L22;
                float b10 = a10*L00 + a11*L10 + a12*L20;
                float b11 = a10*L01 + a11*L11 + a12*L21;
                float b12 = a10*L02 + a11*L12 + a12*L22;
                float c00 = b00*b00 + b01*b01 + b02*b02;
                float c01 = b00*b10 + b01*b11 + b02*b12;   // == c10
                float c11 = b10*b10 + b11*b11 + b12*b12;

                float det = c00*c11 - c01*c01;
                float mid = 0.5f*(c00 + c11);
                float sq  = sqrtf(fmaxf(mid*mid - det, 0.1f));
                float lam = fmaxf(mid + sq, mid - sq);
                float radii = ceilf(3.0f * sqrtf(lam));

                float mx = xyz[3*n+0] * (resf*0.5f);
                float my = xyz[3*n+1] * (resf*0.5f);
                float rminx = fminf(fmaxf(mx - radii, 0.f), resf - 1.f);
                float rmaxx = fminf(fmaxf(mx + radii, 0.f), resf - 1.f);
                float rminy = fminf(fmaxf(my - radii, 0.f), resf - 1.f);
                float rmaxy = fminf(fmaxf(my + radii, 0.f), resf - 1.f);

                bool pass = (fminf(rmaxx, tx1) > fmaxf(rminx, tx0)) &&
                            (fminf(rmaxy, ty1) > fmaxf(rminy, ty0));

                float idet = 1.0f / det;
                const float L2E = 1.44269504088896340736f;
                float A  = -0.5f * L2E * c11 * idet;
                float B  = -0.5f * L2E * c00 * idet;
                float Cc =         L2E * c01 * idet;

                float c3 = -2.f*A*mx - Cc*my;
                float c4 = -2.f*B*my - Cc*mx;
                float c5 = A*mx*mx + B*my*my + Cc*mx*my + log2f(opacity[n]);

                P = make_float4(A, B, Cc, c3);
                Q = make_float2(c4, pass ? c5 : -INFINITY);
            }
            sP[slot] = P;
            sQ[slot] = Q;
        }
        __syncthreads();

        // ---------- accumulate: wave w takes gaussians [w*GPW, (w+1)*GPW) ----------
        const int g0 = w * GPW;
        #pragma unroll 4
        for (int i = g0; i < g0 + GPW; ++i) {
            float4 p  = sP[i];                 // broadcast b128
            float2 qv = sQ[i];                 // broadcast b64
            // scalar part shared by both rows of column a:
            float bse = fmaf(p.x, Xa2, fmaf(p.w, Xa, qv.y));   // A Xa^2 + c3 Xa + c5
            // packed column-a eval at rows (Ya, Yb):
            v2f Q1 = p.y * Y2v + (p.z * XYv + (qv.x * Yv + bse));
            // packed column step dX(y) = A(2Xa+1) + C y + c3:
            float dpre = fmaf(p.x, sXab, p.w);
            v2f DX = p.z * Yv + dpre;
            v2f Q2 = Q1 + DX;
            acc00 += __builtin_amdgcn_exp2f(Q1.x);
            acc01 += __builtin_amdgcn_exp2f(Q1.y);
            acc10 += __builtin_amdgcn_exp2f(Q2.x);
            acc11 += __builtin_amdgcn_exp2f(Q2.y);
        }
        __syncthreads();   // safe to restage LDS next chunk
    }

    // ---------- 16-wave reduce in LDS, plain stores (each pixel written once) ----------
    sR[w][l] = make_float4(acc00, acc10, acc01, acc11);
    __syncthreads();
    if (w == 0) {
        float4 s = sR[0][l];
        #pragma unroll
        for (int k = 1; k < NW; ++k) {
            float4 t = sR[k][l];
            s.x += t.x; s.y += t.y; s.z += t.z; s.w += t.w;
        }
        float* o = out + py0 * res + px0;
        *(float2*)(o)       = make_float2(s.x, s.y);
        *(float2*)(o + res) = make_float2(s.z, s.w);
    }
}

extern "C" void kernel_launch(void* const* d_in, const int* in_sizes, int n_in,
                              void* d_out, int out_size, void* d_ws, size_t ws_size,
                              hipStream_t stream) {
    const float* xyz      = (const float*)d_in[0];
    const float* scaling  = (const float*)d_in[1];
    const float* rotation = (const float*)d_in[2];
    const float* opacity  = (const float*)d_in[3];
    const float* rot      = (const float*)d_in[4];
    int N   = in_sizes[0] / 3;
    int res = (int)(sqrt((double)out_size) + 0.5);
    int nt  = res / TILE;

    float* out = (float*)d_out;

    gs_fused<<<dim3(nt * nt), 1024, 0, stream>>>(
        xyz, scaling, rotation, opacity, rot, out, N, res, nt);
}